// Round 5
// baseline (677.859 us; speedup 1.0000x reference)
//
#include <hip/hip_runtime.h>
#include <hip/hip_bf16.h>
#include <stdint.h>
#include <stddef.h>

#define NN 8192
#define DD 128

typedef __attribute__((ext_vector_type(8))) short bf16x8;
typedef __attribute__((ext_vector_type(4))) float f32x4;

static __device__ __forceinline__ unsigned short f2bf(float x) {
  __hip_bfloat16 h = __float2bfloat16(x);
  return *(unsigned short*)&h;
}
static __device__ __forceinline__ float bf2f(short u) {
  return __uint_as_float(((unsigned int)(unsigned short)u) << 16);
}

// ---------------------------------------------------------------------------
// Kernel 1: row-normalize features (fp32) and cast to bf16. One wave per row.
// ---------------------------------------------------------------------------
__global__ __launch_bounds__(256) void normalize_kernel(
    const float* __restrict__ f, __hip_bfloat16* __restrict__ fn) {
  const int wave = threadIdx.x >> 6;
  const int lane = threadIdx.x & 63;
  const int row = blockIdx.x * 4 + wave;
  const float2 v = ((const float2*)(f + (size_t)row * DD))[lane];
  float ss = v.x * v.x + v.y * v.y;
#pragma unroll
  for (int m = 1; m < 64; m <<= 1) ss += __shfl_xor(ss, m, 64);
  const float inv = 1.0f / fmaxf(sqrtf(ss), 1e-8f);
  __hip_bfloat162 o;
  o.x = __float2bfloat16(v.x * inv);
  o.y = __float2bfloat16(v.y * inv);
  ((__hip_bfloat162*)(fn + (size_t)row * DD))[lane] = o;
}

// ---------------------------------------------------------------------------
// Kernel 2: WAVE-SPECIALIZED. Block = 512 threads: waves 0-3 PRODUCE
// (GEMM 128x128 sim tile via bf16 MFMA, exp -> LDS bf16), waves 4-7 CONSUME
// (pure mask stream + masked accumulate; NO MFMA, no exp, nothing to drain
// their load queue). Double-buffered LDS sim; stage-pipelined with one
// __syncthreads per stage (every wave is wholly producer or consumer, so all
// waves hit the same barrier count).
//
// LDS layout: sim[buf][row][chunk] where a chunk is 16 B (8 bf16 cols);
// physical chunk = (col/8) ^ (row & 15) -- XOR swizzle gives conflict-free
// access in both phases with zero padding (2 x 32 KB = 64 KB static).
//
// Block covers 128 rows x 1024 cols (8 J-tiles); grid (8, 64) = 512 blocks
// -> 2 blocks/CU (LDS- and VGPR-capped), 8 consumer waves/CU streaming.
// ---------------------------------------------------------------------------
__global__ __launch_bounds__(512, 4) void ssnt_main(
    const __hip_bfloat16* __restrict__ fn,
    const int* __restrict__ pmask,
    const int* __restrict__ nmask,
    float* __restrict__ pos, float* __restrict__ neg, float* __restrict__ cnt) {
  __shared__ __hip_bfloat16 sim[2][128 * 128];  // 64 KB, chunk-swizzled

  const int tid = threadIdx.x;
  const int I0g = blockIdx.y * 128;     // row-strip base
  const int Jbase = blockIdx.x * 1024;  // col-span base (8 tiles of 128)

  if (tid < 256) {
    // ======================= PRODUCER (waves 0-3) =======================
    const int lane = tid & 63;
    const int quad = lane >> 4;
    const int l16 = lane & 15;
    const int wx = (tid >> 6) & 1;
    const int wy = tid >> 7;
    const int I0 = I0g + wy * 64;
    const float tinv = 1.0f / 0.07f;

    for (int st = 0; st < 9; ++st) {
      if (st < 8) {
        const int J0 = Jbase + st * 128 + wx * 64;
        // GEMM: fragments straight from L2 (fn = 2 MB, fits per-XCD L2).
        // Swapped operands: i = I0+mt*16+l16, j = J0+nt*16+quad*4+r.
        f32x4 acc[4][4] = {};
#pragma unroll
        for (int kt = 0; kt < 4; ++kt) {
          const int ko = kt * 32 + quad * 8;
          bf16x8 aF[4], bF[4];
#pragma unroll
          for (int mt = 0; mt < 4; ++mt)
            aF[mt] = *(const bf16x8*)(fn + (size_t)(I0 + mt * 16 + l16) * DD + ko);
#pragma unroll
          for (int nt = 0; nt < 4; ++nt)
            bF[nt] = *(const bf16x8*)(fn + (size_t)(J0 + nt * 16 + l16) * DD + ko);
#pragma unroll
          for (int mt = 0; mt < 4; ++mt)
#pragma unroll
            for (int nt = 0; nt < 4; ++nt)
              acc[mt][nt] = __builtin_amdgcn_mfma_f32_16x16x32_bf16(
                  bF[nt], aF[mt], acc[mt][nt], 0, 0, 0);  // SWAPPED
        }
        // exp -> LDS (bf16), 8 B writes at swizzled chunk addresses
        __hip_bfloat16* buf = sim[st & 1];
#pragma unroll
        for (int mt = 0; mt < 4; ++mt) {
          const int iLoc = wy * 64 + mt * 16 + l16;
#pragma unroll
          for (int nt = 0; nt < 4; ++nt) {
            const int jLoc = wx * 64 + nt * 16 + quad * 4;
            const int chunk = (jLoc >> 3) ^ l16;  // iLoc & 15 == l16
            const int half = (jLoc >> 2) & 1;     // which 8 B of the chunk
            ushort4 w;
            w.x = f2bf(__expf(acc[mt][nt][0] * tinv));
            w.y = f2bf(__expf(acc[mt][nt][1] * tinv));
            w.z = f2bf(__expf(acc[mt][nt][2] * tinv));
            w.w = f2bf(__expf(acc[mt][nt][3] * tinv));
            *(ushort4*)((char*)buf + (size_t)iLoc * 256 + chunk * 16 + half * 8) = w;
          }
        }
      }
      __syncthreads();
    }
  } else {
    // ======================= CONSUMER (waves 4-7) =======================
    const int cid = tid - 256;
    const int rGrp = cid >> 4;  // 16 row-groups
    const int cl = cid & 15;    // 16 col-lanes x 8 cols = 128
    const size_t baseOff = (size_t)(I0g + rGrp) * NN + cl * 8 + Jbase;

    float accP[8] = {0.f, 0.f, 0.f, 0.f, 0.f, 0.f, 0.f, 0.f};
    float accQ[8] = {0.f, 0.f, 0.f, 0.f, 0.f, 0.f, 0.f, 0.f};
    int accC[8] = {0, 0, 0, 0, 0, 0, 0, 0};

    // depth-2 rotating mask prefetch (masks are LDS-independent: prologue
    // loads issue before any barrier)
    int4 bP[2][2], bN[2][2];
    {
      const size_t o0 = baseOff;                    // tile 0, subiter 0
      const size_t o1 = baseOff + (size_t)16 * NN;  // tile 0, subiter 1
      bP[0][0] = *(const int4*)(pmask + o0);
      bP[0][1] = *(const int4*)(pmask + o0 + 4);
      bN[0][0] = *(const int4*)(nmask + o0);
      bN[0][1] = *(const int4*)(nmask + o0 + 4);
      bP[1][0] = *(const int4*)(pmask + o1);
      bP[1][1] = *(const int4*)(pmask + o1 + 4);
      bN[1][0] = *(const int4*)(nmask + o1);
      bN[1][1] = *(const int4*)(nmask + o1 + 4);
    }

    const bool diagBlock = ((blockIdx.y >> 3) == blockIdx.x);
    const int diagT = blockIdx.y & 7;

    for (int st = 0; st < 9; ++st) {
      if (st > 0) {
        const int t = st - 1;
        const __hip_bfloat16* buf = sim[t & 1];
        const bool diagTile = diagBlock && (t == diagT);
#pragma unroll
        for (int it = 0; it < 8; ++it) {
          const int s = it & 1;
          int4 cpa = bP[s][0], cpb = bP[s][1];
          int4 cna = bN[s][0], cnb = bN[s][1];
          // refill slot: subiter it+2 of tile t, else subiter it-6 of t+1
          if (it < 6) {
            const size_t o = baseOff + (size_t)(it + 2) * 16 * NN + t * 128;
            bP[s][0] = *(const int4*)(pmask + o);
            bP[s][1] = *(const int4*)(pmask + o + 4);
            bN[s][0] = *(const int4*)(nmask + o);
            bN[s][1] = *(const int4*)(nmask + o + 4);
          } else if (t + 1 < 8) {
            const size_t o = baseOff + (size_t)(it - 6) * 16 * NN + (t + 1) * 128;
            bP[s][0] = *(const int4*)(pmask + o);
            bP[s][1] = *(const int4*)(pmask + o + 4);
            bN[s][0] = *(const int4*)(nmask + o);
            bN[s][1] = *(const int4*)(nmask + o + 4);
          }
          if (diagTile) {  // zero self-contrast (1/64 blocks, 1/8 tiles)
            const int d = (I0g + it * 16 + rGrp) - (Jbase + t * 128 + cl * 8);
#pragma unroll
            for (int r = 0; r < 4; ++r) {
              if (d == r) { (&cpa.x)[r] = 0; (&cna.x)[r] = 0; }
              if (d == r + 4) { (&cpb.x)[r] = 0; (&cnb.x)[r] = 0; }
            }
          }
          const int rLoc = it * 16 + rGrp;
          const int chunk = cl ^ rGrp;  // rLoc & 15 == rGrp
          const bf16x8 ev =
              *(const bf16x8*)((const char*)buf + (size_t)rLoc * 256 + chunk * 16);
          float p = accP[it], q = accQ[it];
          int c = accC[it];
#pragma unroll
          for (int r = 0; r < 8; ++r) {
            const int pm = (r < 4) ? (&cpa.x)[r] : (&cpb.x)[r - 4];
            const int nm = (r < 4) ? (&cna.x)[r] : (&cnb.x)[r - 4];
            const float e = bf2f(ev[r]);
            p = fmaf(e, (float)pm, p);
            q = fmaf(e, (float)nm, q);
            c += pm;
          }
          accP[it] = p; accQ[it] = q; accC[it] = c;
        }
      }
      __syncthreads();
    }

    // epilogue: reduce over 16 col-lanes, one atomic set per row
#pragma unroll
    for (int it = 0; it < 8; ++it) {
      float p = accP[it], q = accQ[it], c = (float)accC[it];
#pragma unroll
      for (int m = 1; m < 16; m <<= 1) {
        p += __shfl_xor(p, m, 64);
        q += __shfl_xor(q, m, 64);
        c += __shfl_xor(c, m, 64);
      }
      const int iG = I0g + it * 16 + rGrp;
      if (cl == 0) atomicAdd(&pos[iG], p);
      else if (cl == 1) atomicAdd(&neg[iG], q);
      else if (cl == 2) atomicAdd(&cnt[iG], c);
    }
  }
}

// ---------------------------------------------------------------------------
// Kernel 3: loss = -mean(log(pos/(pos+neg)) / cnt)
// ---------------------------------------------------------------------------
__global__ __launch_bounds__(256) void finalize_kernel(
    const float* __restrict__ pos, const float* __restrict__ neg,
    const float* __restrict__ cnt, float* __restrict__ out) {
  float s = 0.f;
  for (int i = threadIdx.x; i < NN; i += 256) {
    const float p = pos[i];
    const float q = neg[i];
    s += logf(p / (p + q)) / cnt[i];
  }
#pragma unroll
  for (int m = 1; m < 64; m <<= 1) s += __shfl_xor(s, m, 64);
  __shared__ float wsum[4];
  if ((threadIdx.x & 63) == 0) wsum[threadIdx.x >> 6] = s;
  __syncthreads();
  if (threadIdx.x == 0) {
    out[0] = -(wsum[0] + wsum[1] + wsum[2] + wsum[3]) / (float)NN;
  }
}

extern "C" void kernel_launch(void* const* d_in, const int* in_sizes, int n_in,
                              void* d_out, int out_size, void* d_ws, size_t ws_size,
                              hipStream_t stream) {
  const float* features = (const float*)d_in[0];
  const int* pmask = (const int*)d_in[1];
  const int* nmask = (const int*)d_in[2];
  float* out = (float*)d_out;

  char* ws = (char*)d_ws;
  __hip_bfloat16* fn = (__hip_bfloat16*)ws;  // 2 MB
  float* pos = (float*)(ws + (size_t)NN * DD * sizeof(__hip_bfloat16));
  float* neg = pos + NN;
  float* cnt = neg + NN;

  hipMemsetAsync(pos, 0, 3 * (size_t)NN * sizeof(float), stream);
  normalize_kernel<<<NN / 4, 256, 0, stream>>>(features, fn);
  ssnt_main<<<dim3(8, 64), 512, 0, stream>>>(fn, pmask, nmask, pos, neg, cnt);
  finalize_kernel<<<1, 256, 0, stream>>>(pos, neg, cnt, out);
}

// Round 6
// 630.976 us; speedup vs baseline: 1.0743x; 1.0743x over previous
//
#include <hip/hip_runtime.h>
#include <hip/hip_bf16.h>
#include <stdint.h>
#include <stddef.h>

#define NN 8192
#define DD 128
#define PADW 136  // LDS sim row stride (bf16): breaks power-of-2 bank conflicts

typedef __attribute__((ext_vector_type(8))) short bf16x8;
typedef __attribute__((ext_vector_type(4))) float f32x4;

static __device__ __forceinline__ unsigned short f2bf(float x) {
  __hip_bfloat16 h = __float2bfloat16(x);
  return *(unsigned short*)&h;
}
static __device__ __forceinline__ float bf2f(short u) {
  return __uint_as_float(((unsigned int)(unsigned short)u) << 16);
}

// ---------------------------------------------------------------------------
// Kernel 1: row-normalize features (fp32) and cast to bf16. One wave per row.
// ---------------------------------------------------------------------------
__global__ __launch_bounds__(256) void normalize_kernel(
    const float* __restrict__ f, __hip_bfloat16* __restrict__ fn) {
  const int wave = threadIdx.x >> 6;
  const int lane = threadIdx.x & 63;
  const int row = blockIdx.x * 4 + wave;
  const float2 v = ((const float2*)(f + (size_t)row * DD))[lane];
  float ss = v.x * v.x + v.y * v.y;
#pragma unroll
  for (int m = 1; m < 64; m <<= 1) ss += __shfl_xor(ss, m, 64);
  const float inv = 1.0f / fmaxf(sqrtf(ss), 1e-8f);
  __hip_bfloat162 o;
  o.x = __float2bfloat16(v.x * inv);
  o.y = __float2bfloat16(v.y * inv);
  ((__hip_bfloat162*)(fn + (size_t)row * DD))[lane] = o;
}

// ---------------------------------------------------------------------------
// Kernel 2a: one 128x128 sim tile: bf16 MFMA GEMM (operand-swapped, fragments
// straight from L2 -- fn is 2 MB), exp -> LDS bf16, then COALESCED dwordx4
// stores to the global sim buffer (row-major [NN][span], local columns).
// No mask code -> low VGPR, no spill. (R3-validated GEMM+exp structure.)
// ---------------------------------------------------------------------------
__global__ __launch_bounds__(256, 4) void sim_tile_kernel(
    const __hip_bfloat16* __restrict__ fn, __hip_bfloat16* __restrict__ simg,
    int passJ0, int span) {
  __shared__ __hip_bfloat16 simt[128 * PADW];  // 34 KB

  const int tid = threadIdx.x;
  const int lane = tid & 63;
  const int quad = lane >> 4;
  const int l16 = lane & 15;
  const int wx = (tid >> 6) & 1;
  const int wy = tid >> 7;

  const int I0 = blockIdx.y * 128 + wy * 64;
  const int J0 = passJ0 + blockIdx.x * 128 + wx * 64;  // global col

  // GEMM: swapped operands => i = I0+mt*16+l16, j = J0+nt*16+quad*4+r
  f32x4 acc[4][4] = {};
#pragma unroll
  for (int kt = 0; kt < 4; ++kt) {
    const int ko = kt * 32 + quad * 8;
    bf16x8 aF[4], bF[4];
#pragma unroll
    for (int mt = 0; mt < 4; ++mt)
      aF[mt] = *(const bf16x8*)(fn + (size_t)(I0 + mt * 16 + l16) * DD + ko);
#pragma unroll
    for (int nt = 0; nt < 4; ++nt)
      bF[nt] = *(const bf16x8*)(fn + (size_t)(J0 + nt * 16 + l16) * DD + ko);
#pragma unroll
    for (int mt = 0; mt < 4; ++mt)
#pragma unroll
      for (int nt = 0; nt < 4; ++nt)
        acc[mt][nt] = __builtin_amdgcn_mfma_f32_16x16x32_bf16(
            bF[nt], aF[mt], acc[mt][nt], 0, 0, 0);  // SWAPPED
  }

  // exp(sim/T) -> LDS (bf16)
  const float tinv = 1.0f / 0.07f;
#pragma unroll
  for (int mt = 0; mt < 4; ++mt) {
    const int iLoc = wy * 64 + mt * 16 + l16;
#pragma unroll
    for (int nt = 0; nt < 4; ++nt) {
      const int jLoc = wx * 64 + nt * 16 + quad * 4;
      ushort4 w;
      w.x = f2bf(__expf(acc[mt][nt][0] * tinv));
      w.y = f2bf(__expf(acc[mt][nt][1] * tinv));
      w.z = f2bf(__expf(acc[mt][nt][2] * tinv));
      w.w = f2bf(__expf(acc[mt][nt][3] * tinv));
      *(ushort4*)(simt + iLoc * PADW + jLoc) = w;
    }
  }
  __syncthreads();

  // coalesced store: 16 threads x 16 B per row, 16 rows per pass, 8 passes
  const int r0 = tid >> 4;
  const int c = (tid & 15) * 8;
#pragma unroll
  for (int ps = 0; ps < 8; ++ps) {
    const int r = ps * 16 + r0;
    const bf16x8 v = *(const bf16x8*)(simt + r * PADW + c);
    *(bf16x8*)(simg + (size_t)(blockIdx.y * 128 + r) * span +
               blockIdx.x * 128 + c) = v;
  }
}

// ---------------------------------------------------------------------------
// Kernel 2b: pure streaming masked reduction. One wave per row; each lane
// owns 8 consecutive cols per iter (wave covers 512 cols -> 2 KB contiguous
// per mask load pair). No LDS, no barriers, no MFMA, ~32 VGPRs.
// ---------------------------------------------------------------------------
__global__ __launch_bounds__(256, 4) void reduce_rows_kernel(
    const __hip_bfloat16* __restrict__ simg,
    const int* __restrict__ pmask, const int* __restrict__ nmask,
    float* __restrict__ pos, float* __restrict__ neg, float* __restrict__ cnt,
    int passJ0, int span) {
  const int wave = threadIdx.x >> 6;
  const int lane = threadIdx.x & 63;
  const int row = blockIdx.x * 4 + wave;

  const int iters = span >> 9;  // 512 cols per iter
  const size_t mbase = (size_t)row * NN + passJ0 + lane * 8;
  const __hip_bfloat16* srow = simg + (size_t)row * span + lane * 8;
  const int dloc = row - passJ0;  // local diagonal col if within this pass
  const int diagIt = (dloc >= 0 && dloc < span) ? (dloc >> 9) : -1;

  float p = 0.f, q = 0.f;
  int c = 0;
  for (int it = 0; it < iters; ++it) {
    int4 pa = *(const int4*)(pmask + mbase + (size_t)it * 512);
    int4 pb = *(const int4*)(pmask + mbase + (size_t)it * 512 + 4);
    int4 na = *(const int4*)(nmask + mbase + (size_t)it * 512);
    int4 nb = *(const int4*)(nmask + mbase + (size_t)it * 512 + 4);
    const bf16x8 ev = *(const bf16x8*)(srow + (size_t)it * 512);
    if (it == diagIt) {  // wave-uniform; at most one iter per row
      const int zr = dloc - it * 512 - lane * 8;
#pragma unroll
      for (int r = 0; r < 4; ++r) {
        if (zr == r) { (&pa.x)[r] = 0; (&na.x)[r] = 0; }
        if (zr == r + 4) { (&pb.x)[r] = 0; (&nb.x)[r] = 0; }
      }
    }
#pragma unroll
    for (int r = 0; r < 8; ++r) {
      const int pm = (r < 4) ? (&pa.x)[r] : (&pb.x)[r - 4];
      const int nm = (r < 4) ? (&na.x)[r] : (&nb.x)[r - 4];
      const float e = bf2f(ev[r]);
      p = fmaf(e, (float)pm, p);
      q = fmaf(e, (float)nm, q);
      c += pm;
    }
  }
  // 64-lane butterfly; all lanes end with totals
  float cf = (float)c;
#pragma unroll
  for (int m = 1; m < 64; m <<= 1) {
    p += __shfl_xor(p, m, 64);
    q += __shfl_xor(q, m, 64);
    cf += __shfl_xor(cf, m, 64);
  }
  if (lane == 0) atomicAdd(&pos[row], p);
  else if (lane == 1) atomicAdd(&neg[row], q);
  else if (lane == 2) atomicAdd(&cnt[row], cf);
}

// ---------------------------------------------------------------------------
// Kernel 3: loss = -mean(log(pos/(pos+neg)) / cnt)
// ---------------------------------------------------------------------------
__global__ __launch_bounds__(256) void finalize_kernel(
    const float* __restrict__ pos, const float* __restrict__ neg,
    const float* __restrict__ cnt, float* __restrict__ out) {
  float s = 0.f;
  for (int i = threadIdx.x; i < NN; i += 256) {
    const float p = pos[i];
    const float q = neg[i];
    s += logf(p / (p + q)) / cnt[i];
  }
#pragma unroll
  for (int m = 1; m < 64; m <<= 1) s += __shfl_xor(s, m, 64);
  __shared__ float wsum[4];
  if ((threadIdx.x & 63) == 0) wsum[threadIdx.x >> 6] = s;
  __syncthreads();
  if (threadIdx.x == 0) {
    out[0] = -(wsum[0] + wsum[1] + wsum[2] + wsum[3]) / (float)NN;
  }
}

extern "C" void kernel_launch(void* const* d_in, const int* in_sizes, int n_in,
                              void* d_out, int out_size, void* d_ws, size_t ws_size,
                              hipStream_t stream) {
  const float* features = (const float*)d_in[0];
  const int* pmask = (const int*)d_in[1];
  const int* nmask = (const int*)d_in[2];
  float* out = (float*)d_out;

  char* ws = (char*)d_ws;
  __hip_bfloat16* fn = (__hip_bfloat16*)ws;  // 2 MB
  float* pos = (float*)(ws + (size_t)NN * DD * sizeof(__hip_bfloat16));
  float* neg = pos + NN;
  float* cnt = neg + NN;
  __hip_bfloat16* simg = (__hip_bfloat16*)((char*)(cnt + NN));  // bf16 exp-sim

  // pick the widest column-pass span whose sim slice fits in the workspace
  const size_t fixed = (size_t)NN * DD * 2 + 3 * (size_t)NN * 4;
  int span = 512;
  for (int s = 8192; s >= 512; s >>= 1) {
    if (fixed + (size_t)NN * s * 2 <= ws_size) { span = s; break; }
  }
  const int npass = NN / span;

  hipMemsetAsync(pos, 0, 3 * (size_t)NN * sizeof(float), stream);
  normalize_kernel<<<NN / 4, 256, 0, stream>>>(features, fn);
  for (int ps = 0; ps < npass; ++ps) {
    sim_tile_kernel<<<dim3(span / 128, NN / 128), 256, 0, stream>>>(
        fn, simg, ps * span, span);
    reduce_rows_kernel<<<NN / 4, 256, 0, stream>>>(
        simg, pmask, nmask, pos, neg, cnt, ps * span, span);
  }
  finalize_kernel<<<1, 256, 0, stream>>>(pos, neg, cnt, out);
}